// Round 3
// baseline (499.796 us; speedup 1.0000x reference)
//
#include <hip/hip_runtime.h>
#include <math.h>

#define B_ 128
#define N_ 128
#define D_ 64
#define H_ 8
#define DH_ 64
#define NEGF (-1e30f)

__device__ __forceinline__ float wred(float v) {
#pragma unroll
  for (int off = 32; off > 0; off >>= 1) v += __shfl_xor(v, off, 64);
  return v;
}

__device__ __forceinline__ float gelu_f(float x) {
  return 0.5f * x * (1.f + erff(x * 0.70710678118654752440f));
}

// K2: fused embed (e = x*Wemb+bemb), h = RMS(e), lne = LN1(e), then
// q/k/v = h @ Wq/Wk/Wv (scattered to B,H,N,DH) and g = sigmoid(h@Wg+bg).
// 32 rows per block; weight panels streamed once per 32 rows.
__global__ void k2_embed_proj(const float* __restrict__ x, const float* __restrict__ Wemb,
                              const float* __restrict__ bemb, const float* __restrict__ rmsg,
                              const float* __restrict__ ln1g, const float* __restrict__ ln1b,
                              const float* __restrict__ Wq, const float* __restrict__ Wk,
                              const float* __restrict__ Wv, const float* __restrict__ Wg,
                              const float* __restrict__ bg, float* __restrict__ e,
                              float* __restrict__ lne, float* __restrict__ q,
                              float* __restrict__ k, float* __restrict__ v,
                              float* __restrict__ g) {
  __shared__ __align__(16) float hs[32][64];
  int tid = threadIdx.x;
  int r0 = blockIdx.x * 32;
  int wave = tid >> 6, lane = tid & 63;
  // ---- embed + RMS + LN1 for 32 rows (8 rows per wave, lane = d) ----
  for (int rr = 0; rr < 8; ++rr) {
    int r = wave * 8 + rr;
    int row = r0 + r;
    float xv = x[row];
    float ev = fmaf(xv, Wemb[lane], bemb[lane]);
    float ss = wred(ev * ev) * (1.f / 64.f);
    float hv = ev * rsqrtf(ss + 1e-6f) * rmsg[lane];
    float mu = wred(ev) * (1.f / 64.f);
    float dv = ev - mu;
    float var = wred(dv * dv) * (1.f / 64.f);
    float lv = dv * rsqrtf(var + 1e-5f) * ln1g[lane] + ln1b[lane];
    size_t o = (size_t)row * 64 + lane;
    e[o] = ev; lne[o] = lv;
    hs[r][lane] = hv;
  }
  __syncthreads();
  // ---- projections ----
  for (int c = tid; c < 1560; c += 256) {
    if (c < 1536) {
      int mat = c >> 9, cc = c & 511;
      const float* W = (mat == 0) ? Wq : ((mat == 1) ? Wk : Wv);
      float acc[32];
#pragma unroll
      for (int r = 0; r < 32; ++r) acc[r] = 0.f;
      for (int k4 = 0; k4 < 16; ++k4) {
        float w0 = W[(4 * k4 + 0) * 512 + cc];
        float w1 = W[(4 * k4 + 1) * 512 + cc];
        float w2 = W[(4 * k4 + 2) * 512 + cc];
        float w3 = W[(4 * k4 + 3) * 512 + cc];
#pragma unroll
        for (int r = 0; r < 32; ++r) {
          float4 hv = *(const float4*)&hs[r][4 * k4];
          acc[r] = fmaf(w0, hv.x, fmaf(w1, hv.y, fmaf(w2, hv.z, fmaf(w3, hv.w, acc[r]))));
        }
      }
      float* dst = (mat == 0) ? q : ((mat == 1) ? k : v);
      int hh = cc >> 6, d = cc & 63;
#pragma unroll
      for (int r = 0; r < 32; ++r) {
        int row = r0 + r; int bb = row >> 7, nn = row & 127;
        dst[(((size_t)bb * 8 + hh) * 128 + nn) * 64 + d] = acc[r];
      }
    } else {
      int gc = c - 1536;
      float acc[32];
#pragma unroll
      for (int r = 0; r < 32; ++r) acc[r] = 0.f;
      for (int k4 = 0; k4 < 16; ++k4) {
        float w0 = Wg[(4 * k4 + 0) * 24 + gc];
        float w1 = Wg[(4 * k4 + 1) * 24 + gc];
        float w2 = Wg[(4 * k4 + 2) * 24 + gc];
        float w3 = Wg[(4 * k4 + 3) * 24 + gc];
#pragma unroll
        for (int r = 0; r < 32; ++r) {
          float4 hv = *(const float4*)&hs[r][4 * k4];
          acc[r] = fmaf(w0, hv.x, fmaf(w1, hv.y, fmaf(w2, hv.z, fmaf(w3, hv.w, acc[r]))));
        }
      }
#pragma unroll
      for (int r = 0; r < 32; ++r)
        g[(size_t)(r0 + r) * 24 + gc] = 1.f / (1.f + __expf(-(acc[r] + bg[gc])));
    }
  }
}

// K3: per (b,h): ck = (k+kpos) @ Wck + bck ; cv = (v+vpos) @ Wcv + bcv; plus mem slot 0.
__global__ void k3_compress(const float* __restrict__ k, const float* __restrict__ v,
                            const float* __restrict__ kpos, const float* __restrict__ vpos,
                            const float* __restrict__ Wck, const float* __restrict__ bck,
                            const float* __restrict__ Wcv, const float* __restrict__ bcv,
                            const float* __restrict__ mck, const float* __restrict__ mcv,
                            float* __restrict__ ckm, float* __restrict__ cvm) {
  __shared__ __align__(16) float sb[8192];
  int bh = blockIdx.x; int hh = bh & 7;
  int tid = threadIdx.x;
  int d = tid & 63, nbase = (tid >> 6) * 8;
  const float4* sb4 = (const float4*)sb;  // [32 block-rows][64 float4]
  // keys
  for (int idx = tid; idx < 8192; idx += 256) {
    int tok = idx >> 6, dd = idx & 63;
    sb[idx] = k[(size_t)bh * 8192 + idx] + kpos[(hh * 4 + (tok & 3)) * 64 + dd];
  }
  __syncthreads();
  {
    float acc[8];
#pragma unroll
    for (int i = 0; i < 8; ++i) acc[i] = bck[d];
    for (int j4 = 0; j4 < 64; ++j4) {
      float w0 = Wck[(4 * j4 + 0) * 64 + d];
      float w1 = Wck[(4 * j4 + 1) * 64 + d];
      float w2 = Wck[(4 * j4 + 2) * 64 + d];
      float w3 = Wck[(4 * j4 + 3) * 64 + d];
#pragma unroll
      for (int i = 0; i < 8; ++i) {
        float4 sv = sb4[(nbase + i) * 64 + j4];
        acc[i] = fmaf(w0, sv.x, fmaf(w1, sv.y, fmaf(w2, sv.z, fmaf(w3, sv.w, acc[i]))));
      }
    }
#pragma unroll
    for (int i = 0; i < 8; ++i) ckm[((size_t)bh * 33 + nbase + i + 1) * 64 + d] = acc[i];
    if (tid < 64) ckm[(size_t)bh * 33 * 64 + tid] = mck[hh * 64 + tid];
  }
  __syncthreads();
  // values
  for (int idx = tid; idx < 8192; idx += 256) {
    int tok = idx >> 6, dd = idx & 63;
    sb[idx] = v[(size_t)bh * 8192 + idx] + vpos[(hh * 4 + (tok & 3)) * 64 + dd];
  }
  __syncthreads();
  {
    float acc[8];
#pragma unroll
    for (int i = 0; i < 8; ++i) acc[i] = bcv[d];
    for (int j4 = 0; j4 < 64; ++j4) {
      float w0 = Wcv[(4 * j4 + 0) * 64 + d];
      float w1 = Wcv[(4 * j4 + 1) * 64 + d];
      float w2 = Wcv[(4 * j4 + 2) * 64 + d];
      float w3 = Wcv[(4 * j4 + 3) * 64 + d];
#pragma unroll
      for (int i = 0; i < 8; ++i) {
        float4 sv = sb4[(nbase + i) * 64 + j4];
        acc[i] = fmaf(w0, sv.x, fmaf(w1, sv.y, fmaf(w2, sv.z, fmaf(w3, sv.w, acc[i]))));
      }
    }
#pragma unroll
    for (int i = 0; i < 8; ++i) cvm[((size_t)bh * 33 + nbase + i + 1) * 64 + d] = acc[i];
    if (tid < 64) cvm[(size_t)bh * 33 * 64 + tid] = mcv[hh * 64 + tid];
  }
}

// K4: per (b,h): compressed + selected + window attention, gated combine. 1 thread = 1 query.
// Scores live in registers (thread-private); ckm/cvm rows are block-uniform -> scalar loads.
#define KLD 68  // K/V LDS row stride: 272B, 16B-aligned, rows spread over 8 bank groups
__global__ void __launch_bounds__(128, 2) k4_attn(
    const float* __restrict__ q, const float* __restrict__ k, const float* __restrict__ v,
    const float* __restrict__ ckm, const float* __restrict__ cvm, const float* __restrict__ g,
    float* __restrict__ attn) {
  __shared__ __align__(16) float ks[128 * KLD];  // K rows, later reloaded with V rows
  int bh = blockIdx.x; int b = bh >> 3, hh = bh & 7;
  int tid = threadIdx.x;
  for (int idx = tid; idx < 8192; idx += 128)
    ks[(idx >> 6) * KLD + (idx & 63)] = k[(size_t)bh * 8192 + idx];
  __syncthreads();
  const int n = tid;
  float4 qr[16];
  {
    const float4* q4 = (const float4*)(q + (size_t)bh * 8192 + (size_t)n * 64);
#pragma unroll
    for (int i = 0; i < 16; ++i) {
      float4 t = q4[i];
      t.x *= 0.125f; t.y *= 0.125f; t.z *= 0.125f; t.w *= 0.125f;  // fold scale into q
      qr[i] = t;
    }
  }
  auto dot = [&](const float4* __restrict__ rp) {
    float s = 0.f;
#pragma unroll
    for (int i = 0; i < 16; ++i) {
      float4 c = rp[i];
      s = fmaf(qr[i].x, c.x, s); s = fmaf(qr[i].y, c.y, s);
      s = fmaf(qr[i].z, c.z, s); s = fmaf(qr[i].w, c.w, s);
    }
    return s;
  };
  // ---- compressed scores (33) in registers ----
  const float* ck0 = ckm + (size_t)bh * 2112;
  const int jmax = (n + 1) >> 2;  // slot j (>=1) valid iff n >= 4(j-1)+3
  float scc[33];
#pragma unroll
  for (int j = 0; j < 33; ++j) {
    float s = dot((const float4*)(ck0 + j * 64));
    scc[j] = (j == 0 || j <= jmax) ? s : NEGF;
  }
  // ---- exact top-2 over blocks (strict >, first index wins = lax.top_k ties) ----
  int i1 = 0; float b1 = scc[1];
#pragma unroll
  for (int j = 2; j < 33; ++j) {
    if (scc[j] > b1) { b1 = scc[j]; i1 = j - 1; }
  }
  int i2 = 0; float b2 = -3.0e38f;
#pragma unroll
  for (int j = 1; j < 33; ++j) {
    if ((j - 1 != i1) && (scc[j] > b2)) { b2 = scc[j]; i2 = j - 1; }
  }
  const int qb = n >> 2;
  const bool ok1 = (b1 > -5e29f) && (i1 != qb);
  const bool ok2 = (b2 > -5e29f) && (i2 != qb);
  const int row1 = i1 * 4, row2 = i2 * 4, rowd = qb * 4;
  // ---- fine scores (12) ----
  float sf[12];
#pragma unroll
  for (int s2 = 0; s2 < 4; ++s2) {
    int t1 = row1 + s2;
    sf[s2] = (ok1 && t1 <= n) ? dot((const float4*)(ks + t1 * KLD)) : NEGF;
    int t2 = row2 + s2;
    sf[4 + s2] = (ok2 && t2 <= n) ? dot((const float4*)(ks + t2 * KLD)) : NEGF;
    int t3 = rowd + s2;
    sf[8 + s2] = (t3 <= n) ? dot((const float4*)(ks + t3 * KLD)) : NEGF;
  }
  // ---- window scores (2) ----
  float sw0 = (n >= 1) ? dot((const float4*)(ks + (n - 1) * KLD)) : NEGF;
  float sw1 = dot((const float4*)(ks + n * KLD));
  __syncthreads();
  for (int idx = tid; idx < 8192; idx += 128)  // reload LDS with V
    ks[(idx >> 6) * KLD + (idx & 63)] = v[(size_t)bh * 8192 + idx];
  __syncthreads();
  // ---- softmaxes (all in registers) ----
  float mxc = scc[0];
#pragma unroll
  for (int j = 1; j < 33; ++j) mxc = fmaxf(mxc, scc[j]);
  float denc = 0.f;
#pragma unroll
  for (int j = 0; j < 33; ++j) { float p = __expf(scc[j] - mxc); scc[j] = p; denc += p; }
  float mxf = sf[0];
#pragma unroll
  for (int i = 1; i < 12; ++i) mxf = fmaxf(mxf, sf[i]);
  float denf = 0.f;
#pragma unroll
  for (int i = 0; i < 12; ++i) { float p = __expf(sf[i] - mxf); sf[i] = p; denf += p; }
  float mxw = fmaxf(sw0, sw1);
  float pw0 = __expf(sw0 - mxw), pw1 = __expf(sw1 - mxw);
  // ---- gates folded into per-stream normalization ----
  const float* gr = g + (size_t)(b * 128 + n) * 24;
  float gc0 = gr[hh] / denc;
  float gf0 = gr[8 + hh] / denf;
  float gw0 = gr[16 + hh] / (pw0 + pw1);
  // ---- PV accumulate ----
  float4 oa[16];
#pragma unroll
  for (int i = 0; i < 16; ++i) oa[i] = make_float4(0.f, 0.f, 0.f, 0.f);
  const float* cv0 = cvm + (size_t)bh * 2112;
#pragma unroll
  for (int j = 0; j < 33; ++j) {
    float p = scc[j] * gc0;
    const float4* cr = (const float4*)(cv0 + j * 64);
#pragma unroll
    for (int i = 0; i < 16; ++i) {
      float4 c = cr[i];
      oa[i].x = fmaf(p, c.x, oa[i].x); oa[i].y = fmaf(p, c.y, oa[i].y);
      oa[i].z = fmaf(p, c.z, oa[i].z); oa[i].w = fmaf(p, c.w, oa[i].w);
    }
  }
#pragma unroll
  for (int si = 0; si < 12; ++si) {
    int tok = ((si < 4) ? row1 : (si < 8) ? row2 : rowd) + (si & 3);
    float p = sf[si] * gf0;
    const float4* vr = (const float4*)(ks + tok * KLD);
#pragma unroll
    for (int i = 0; i < 16; ++i) {
      float4 c = vr[i];
      oa[i].x = fmaf(p, c.x, oa[i].x); oa[i].y = fmaf(p, c.y, oa[i].y);
      oa[i].z = fmaf(p, c.z, oa[i].z); oa[i].w = fmaf(p, c.w, oa[i].w);
    }
  }
  {
    int nm1 = (n >= 1) ? (n - 1) : 0;
    float p0 = pw0 * gw0, p1 = pw1 * gw0;
    const float4* v0 = (const float4*)(ks + nm1 * KLD);
    const float4* v1 = (const float4*)(ks + n * KLD);
#pragma unroll
    for (int i = 0; i < 16; ++i) {
      float4 c0 = v0[i], c1 = v1[i];
      oa[i].x = fmaf(p0, c0.x, fmaf(p1, c1.x, oa[i].x));
      oa[i].y = fmaf(p0, c0.y, fmaf(p1, c1.y, oa[i].y));
      oa[i].z = fmaf(p0, c0.z, fmaf(p1, c1.z, oa[i].z));
      oa[i].w = fmaf(p0, c0.w, fmaf(p1, c1.w, oa[i].w));
    }
  }
  float4* arow = (float4*)(attn + ((size_t)(b * 128 + n)) * 512 + hh * 64);
#pragma unroll
  for (int i = 0; i < 16; ++i) arow[i] = oa[i];
}

// K5: x1 = attn @ Wo. 16 rows per block.
__global__ void k5_wo(const float* __restrict__ attn, const float* __restrict__ Wo,
                      float* __restrict__ x1) {
  __shared__ __align__(16) float as[8192];
  int tid = threadIdx.x;
  size_t base = (size_t)blockIdx.x * 8192;
  for (int idx = tid; idx < 8192; idx += 256) as[idx] = attn[base + idx];
  __syncthreads();
  int d = tid & 63, rb = tid >> 6;
  const float4* as4 = (const float4*)as;  // [16 rows][128 float4]
  float acc[4] = {0.f, 0.f, 0.f, 0.f};
  for (int j4 = 0; j4 < 128; ++j4) {
    float w0 = Wo[(4 * j4 + 0) * 64 + d];
    float w1 = Wo[(4 * j4 + 1) * 64 + d];
    float w2 = Wo[(4 * j4 + 2) * 64 + d];
    float w3 = Wo[(4 * j4 + 3) * 64 + d];
#pragma unroll
    for (int i = 0; i < 4; ++i) {
      float4 a = as4[(rb * 4 + i) * 128 + j4];
      acc[i] = fmaf(a.x, w0, fmaf(a.y, w1, fmaf(a.z, w2, fmaf(a.w, w3, acc[i]))));
    }
  }
  size_t r0 = (size_t)blockIdx.x * 16;
#pragma unroll
  for (int i = 0; i < 4; ++i) x1[(r0 + rb * 4 + i) * 64 + d] = acc[i];
}

// K6: token mixer. block = (b, 8 d-cols): m = e + (gelu(LN1(e)^T @ Wt1 + bt1) @ Wt2 + bt2)^T
__global__ void k6_token(const float* __restrict__ lne, const float* __restrict__ e,
                         const float* __restrict__ Wt1, const float* __restrict__ bt1,
                         const float* __restrict__ Wt2, const float* __restrict__ bt2,
                         float* __restrict__ m) {
  __shared__ __align__(16) float trow[8][128];
  __shared__ __align__(16) float hid[8][256];
  int b = blockIdx.x >> 3, d0 = (blockIdx.x & 7) * 8;
  int tid = threadIdx.x;
  for (int idx = tid; idx < 1024; idx += 256) {
    int nn = idx >> 3, dl = idx & 7;
    trow[dl][nn] = lne[((size_t)b * 128 + nn) * 64 + d0 + dl];
  }
  __syncthreads();
  {
    float acc[8];
#pragma unroll
    for (int i = 0; i < 8; ++i) acc[i] = 0.f;
    for (int n4 = 0; n4 < 32; ++n4) {
      float w0 = Wt1[(4 * n4 + 0) * 256 + tid];
      float w1 = Wt1[(4 * n4 + 1) * 256 + tid];
      float w2 = Wt1[(4 * n4 + 2) * 256 + tid];
      float w3 = Wt1[(4 * n4 + 3) * 256 + tid];
#pragma unroll
      for (int i = 0; i < 8; ++i) {
        float4 t = *(const float4*)&trow[i][4 * n4];
        acc[i] = fmaf(w0, t.x, fmaf(w1, t.y, fmaf(w2, t.z, fmaf(w3, t.w, acc[i]))));
      }
    }
    float bb = bt1[tid];
#pragma unroll
    for (int i = 0; i < 8; ++i) hid[i][tid] = gelu_f(acc[i] + bb);
  }
  __syncthreads();
  for (int idx = tid; idx < 1024; idx += 256) {
    int nn = idx & 127, dl = idx >> 7;
    float o = bt2[nn];
    for (int j4 = 0; j4 < 64; ++j4) {
      float4 hv = *(const float4*)&hid[dl][4 * j4];
      o = fmaf(hv.x, Wt2[(4 * j4 + 0) * 128 + nn],
          fmaf(hv.y, Wt2[(4 * j4 + 1) * 128 + nn],
          fmaf(hv.z, Wt2[(4 * j4 + 2) * 128 + nn],
          fmaf(hv.w, Wt2[(4 * j4 + 3) * 128 + nn], o))));
    }
    size_t oi = ((size_t)b * 128 + nn) * 64 + d0 + dl;
    m[oi] = e[oi] + o;
  }
}

// K7: channel MLP in-place: m += gelu(LN2(m) @ Wc1 + bc1) @ Wc2 + bc2. 16 rows/block.
__global__ void k7_channel(float* __restrict__ m, const float* __restrict__ g2,
                           const float* __restrict__ b2, const float* __restrict__ Wc1,
                           const float* __restrict__ bc1, const float* __restrict__ Wc2,
                           const float* __restrict__ bc2) {
  __shared__ __align__(16) float lnr[16][64];
  __shared__ __align__(16) float hid[16][256];
  int tid = threadIdx.x;
  int wv = tid >> 6, lane = tid & 63;
  size_t r0 = (size_t)blockIdx.x * 16;
  for (int rr = 0; rr < 4; ++rr) {
    int r = wv * 4 + rr;
    float mv = m[(r0 + r) * 64 + lane];
    float mu = wred(mv) * (1.f / 64.f);
    float dv = mv - mu;
    float var = wred(dv * dv) * (1.f / 64.f);
    lnr[r][lane] = dv * rsqrtf(var + 1e-5f) * g2[lane] + b2[lane];
  }
  __syncthreads();
  {
    float acc[16];
#pragma unroll
    for (int r = 0; r < 16; ++r) acc[r] = 0.f;
    for (int k4 = 0; k4 < 16; ++k4) {
      float w0 = Wc1[(4 * k4 + 0) * 256 + tid];
      float w1 = Wc1[(4 * k4 + 1) * 256 + tid];
      float w2 = Wc1[(4 * k4 + 2) * 256 + tid];
      float w3 = Wc1[(4 * k4 + 3) * 256 + tid];
#pragma unroll
      for (int r = 0; r < 16; ++r) {
        float4 t = *(const float4*)&lnr[r][4 * k4];
        acc[r] = fmaf(w0, t.x, fmaf(w1, t.y, fmaf(w2, t.z, fmaf(w3, t.w, acc[r]))));
      }
    }
    float bb = bc1[tid];
#pragma unroll
    for (int r = 0; r < 16; ++r) hid[r][tid] = gelu_f(acc[r] + bb);
  }
  __syncthreads();
  {
    float acc[4];
#pragma unroll
    for (int i = 0; i < 4; ++i) acc[i] = bc2[lane];
    for (int j4 = 0; j4 < 64; ++j4) {
      float w0 = Wc2[(4 * j4 + 0) * 64 + lane];
      float w1 = Wc2[(4 * j4 + 1) * 64 + lane];
      float w2 = Wc2[(4 * j4 + 2) * 64 + lane];
      float w3 = Wc2[(4 * j4 + 3) * 64 + lane];
#pragma unroll
      for (int i = 0; i < 4; ++i) {
        float4 t = *(const float4*)&hid[wv * 4 + i][4 * j4];
        acc[i] = fmaf(w0, t.x, fmaf(w1, t.y, fmaf(w2, t.z, fmaf(w3, t.w, acc[i]))));
      }
    }
#pragma unroll
    for (int i = 0; i < 4; ++i) {
      size_t oi = (r0 + wv * 4 + i) * 64 + lane;
      m[oi] = m[oi] + acc[i];
    }
  }
}

// K8: y = mean_n(x1+m); out = gelu(y@Wh1+bh1)@Wh2 + bh2. One wave per batch row.
__global__ void k8_head(const float* __restrict__ x1, const float* __restrict__ m,
                        const float* __restrict__ Wh1, const float* __restrict__ bh1,
                        const float* __restrict__ Wh2, const float* __restrict__ bh2,
                        float* __restrict__ out) {
  __shared__ float ys[64];
  int b = blockIdx.x, lane = threadIdx.x;
  float acc = 0.f;
  for (int nn = 0; nn < 128; ++nn) {
    size_t oi = ((size_t)b * 128 + nn) * 64 + lane;
    acc += x1[oi] + m[oi];
  }
  ys[lane] = acc * (1.f / 128.f);
  __syncthreads();
  float partial = 0.f;
  if (lane < 32) {
    float a = bh1[lane];
    for (int dd = 0; dd < 64; ++dd) a = fmaf(ys[dd], Wh1[dd * 32 + lane], a);
    partial = gelu_f(a) * Wh2[lane];
  }
  partial = wred(partial);
  if (lane == 0) out[b] = partial + bh2[0];
}

extern "C" void kernel_launch(void* const* d_in, const int* in_sizes, int n_in,
                              void* d_out, int out_size, void* d_ws, size_t ws_size,
                              hipStream_t stream) {
  const float* x     = (const float*)d_in[0];
  const float* Wemb  = (const float*)d_in[1];
  const float* bemb  = (const float*)d_in[2];
  const float* rmsg  = (const float*)d_in[3];
  const float* Wq    = (const float*)d_in[4];
  const float* Wk    = (const float*)d_in[5];
  const float* Wv    = (const float*)d_in[6];
  const float* kpos  = (const float*)d_in[7];
  const float* vpos  = (const float*)d_in[8];
  const float* Wck   = (const float*)d_in[9];
  const float* bck   = (const float*)d_in[10];
  const float* Wcv   = (const float*)d_in[11];
  const float* bcv   = (const float*)d_in[12];
  const float* mck   = (const float*)d_in[13];
  const float* mcv   = (const float*)d_in[14];
  const float* Wg    = (const float*)d_in[15];
  const float* bg    = (const float*)d_in[16];
  const float* Wo    = (const float*)d_in[17];
  const float* ln1g  = (const float*)d_in[18];
  const float* ln1b  = (const float*)d_in[19];
  const float* Wt1   = (const float*)d_in[20];
  const float* bt1   = (const float*)d_in[21];
  const float* Wt2   = (const float*)d_in[22];
  const float* bt2   = (const float*)d_in[23];
  const float* ln2g  = (const float*)d_in[24];
  const float* ln2b  = (const float*)d_in[25];
  const float* Wc1   = (const float*)d_in[26];
  const float* bc1   = (const float*)d_in[27];
  const float* Wc2   = (const float*)d_in[28];
  const float* bc2   = (const float*)d_in[29];
  const float* Wh1   = (const float*)d_in[30];
  const float* bh1   = (const float*)d_in[31];
  const float* Wh2   = (const float*)d_in[32];
  const float* bh2   = (const float*)d_in[33];

  float* ws = (float*)d_ws;
  const size_t SZ_ROWD = (size_t)B_ * N_ * D_;        // 1,048,576
  const size_t SZ_BHND = (size_t)B_ * H_ * N_ * DH_;  // 8,388,608
  float* e    = ws;                    // SZ_ROWD
  float* lne  = e + SZ_ROWD;           // SZ_ROWD
  float* q    = lne + SZ_ROWD;         // SZ_BHND
  float* k    = q + SZ_BHND;           // SZ_BHND (x1 aliases after K4)
  float* v    = k + SZ_BHND;           // SZ_BHND (m aliases after K4)
  float* g    = v + SZ_BHND;           // B*N*24
  float* ckm  = g + (size_t)B_ * N_ * 24;         // B*H*33*64
  float* cvm  = ckm + (size_t)B_ * H_ * 33 * 64;  // B*H*33*64
  float* attn = cvm + (size_t)B_ * H_ * 33 * 64;  // B*N*512
  float* x1   = k;   // k is dead after K4; K5 writes x1 here
  float* m    = v;   // v is dead after K4; K6 writes m here

  k2_embed_proj<<<dim3(B_ * N_ / 32), dim3(256), 0, stream>>>(
      x, Wemb, bemb, rmsg, ln1g, ln1b, Wq, Wk, Wv, Wg, bg, e, lne, q, k, v, g);
  k3_compress<<<dim3(B_ * H_), dim3(256), 0, stream>>>(k, v, kpos, vpos, Wck, bck, Wcv, bcv, mck, mcv, ckm, cvm);
  k4_attn<<<dim3(B_ * H_), dim3(128), 0, stream>>>(q, k, v, ckm, cvm, g, attn);
  k5_wo<<<dim3(B_ * N_ / 16), dim3(256), 0, stream>>>(attn, Wo, x1);
  k6_token<<<dim3(B_ * (D_ / 8)), dim3(256), 0, stream>>>(lne, e, Wt1, bt1, Wt2, bt2, m);
  k7_channel<<<dim3(B_ * N_ / 16), dim3(256), 0, stream>>>(m, ln2g, ln2b, Wc1, bc1, Wc2, bc2);
  k8_head<<<dim3(B_), dim3(64), 0, stream>>>(x1, m, Wh1, bh1, Wh2, bh2, (float*)d_out);
}